// Round 12
// baseline (344.669 us; speedup 1.0000x reference)
//
#include <hip/hip_runtime.h>
#include <hip/hip_bf16.h>
#include <math.h>

#define SEQ 2048
#define NH 16
#define HD 128
#define HID 2048
#define KVB 64
#define NKT (SEQ/KVB)
#define QB 128              // q rows per block (4 waves x 32)
#define QBLK 64             // f32 fallback kernel

typedef __attribute__((ext_vector_type(8))) short bf16x8;
typedef __attribute__((ext_vector_type(4))) short bf16x4;
typedef __attribute__((ext_vector_type(4))) float f32x4;
typedef __attribute__((ext_vector_type(16))) float f32x16;
typedef __attribute__((ext_vector_type(2))) unsigned uint2v;

#define SCL2E 0.1275310261f            // (1/sqrt(128)) * log2(e)
#define L2E   1.4426950408889634f

__device__ __forceinline__ short f2bf(float x){
  __hip_bfloat16 h = __float2bfloat16(x);
  return *reinterpret_cast<short*>(&h);
}
__device__ __forceinline__ unsigned cvtpk(float lo, float hi){
  unsigned r;
  asm("v_cvt_pk_bf16_f32 %0, %1, %2" : "=v"(r) : "v"(lo), "v"(hi));
  return r;
}
__device__ __forceinline__ void gld_lds16(const void* g, void* l){
  __builtin_amdgcn_global_load_lds((const __attribute__((address_space(1))) void*)g,
                                   (__attribute__((address_space(3))) void*)l, 16, 0, 0);
}
// s_barrier is NOT a compiler memory fence (round-8 lesson): pin both sides.
__device__ __forceinline__ void block_barrier(){
  asm volatile("" ::: "memory");
  __builtin_amdgcn_sched_barrier(0);
  __builtin_amdgcn_s_barrier();
  __builtin_amdgcn_sched_barrier(0);
  asm volatile("" ::: "memory");
}

// ---- fused pre-pass + mask scan ----
// all blocks: grid-stride scan of mask (flag |= any nonzero)
// blocks [0,2048):   K  fp32 [b][s][h*d] -> bf16 [b][h][s][d]
// blocks [2048,3072): V  fp32 [b][s][h*d] -> bf16 V^T [b][h][d][s]
__global__ void cvt_kv_k(const float* __restrict__ Kg, const float* __restrict__ Vg,
                         const float* __restrict__ Mg,
                         short* __restrict__ Kb, short* __restrict__ Vt,
                         int* __restrict__ flag){
  __shared__ short T[64*HD];
  const int tid = threadIdx.x;
  {
    // mask scan slice (16 MB over 3072 blocks)
    const int n4m = SEQ*SEQ/4;
    int any = 0;
    const float4* m4 = (const float4*)Mg;
    for (int i = blockIdx.x*256 + tid; i < n4m; i += 3072*256){
      float4 v = m4[i];
      any |= (v.x != 0.f) | (v.y != 0.f) | (v.z != 0.f) | (v.w != 0.f);
    }
    if (__ballot(any) != 0ull && (tid & 63) == 0) atomicOr(flag, 1);
  }
  if (blockIdx.x < 2048){
    const int n4 = (2*SEQ*HID)/4;
    for (int i = blockIdx.x*256 + tid; i < n4; i += 2048*256){
      int i4 = i*4;
      int b   = i4 >> 22;
      int rem = i4 & ((1<<22)-1);
      int s   = rem >> 11;
      int hd  = rem & 2047;
      int h = hd >> 7, d = hd & 127;
      float4 v = *(const float4*)(Kg + i4);
      bf16x4 o; o[0]=f2bf(v.x); o[1]=f2bf(v.y); o[2]=f2bf(v.z); o[3]=f2bf(v.w);
      *(bf16x4*)(Kb + ((size_t)((b*NH + h)*SEQ + s))*HD + d) = o;
    }
  } else {
    const int bid = blockIdx.x - 2048;
    const int bh = bid >> 5, st = bid & 31;
    const int b = bh >> 4, h = bh & 15;
    const int s0 = st*64;
    const float* vp = Vg + ((size_t)(b*SEQ + s0))*HID + h*HD;
    #pragma unroll
    for (int i = 0; i < 8; ++i){
      int idx = tid + i*256;
      int r = idx >> 5, c4 = idx & 31;
      float4 v = *(const float4*)(vp + (size_t)r*HID + c4*4);
      int X = ((r & 7) ^ ((r >> 3) & 7)) << 3;
      bf16x4 o; o[0]=f2bf(v.x); o[1]=f2bf(v.y); o[2]=f2bf(v.z); o[3]=f2bf(v.w);
      *(bf16x4*)(&T[r*HD + ((c4*4) ^ X)]) = o;
    }
    __syncthreads();
    short* op = Vt + ((size_t)bh*HD)*SEQ + s0;
    #pragma unroll
    for (int u = 0; u < 4; ++u){
      int unit = tid + u*256;
      int sb = unit & 7, d = unit >> 3;
      bf16x8 pk;
      #pragma unroll
      for (int j = 0; j < 8; ++j)
        pk[j] = T[(sb*8 + j)*HD + (d ^ (((j ^ sb) & 7) << 3))];
      *(bf16x8*)(op + (size_t)d*SEQ + sb*8) = pk;
    }
  }
}

// standalone mask scan (fallback path only)
__global__ void mask_scan_k(const float* __restrict__ m, int n4, int* __restrict__ flag){
  int any = 0;
  const float4* m4 = (const float4*)m;
  for (int i = blockIdx.x*blockDim.x + threadIdx.x; i < n4; i += gridDim.x*blockDim.x){
    float4 v = m4[i];
    any |= (v.x != 0.f) | (v.y != 0.f) | (v.z != 0.f) | (v.w != 0.f);
  }
  if (__ballot(any) != 0ull && (threadIdx.x & 63) == 0) atomicOr(flag, 1);
}

// ---- main: 512 blocks, 4 waves x 32 q-rows, counted-vmcnt software pipeline ----
// vs r11: row-max/rescale of softmax(T) moved PRE-barrier (fills the vmcnt stall;
// depends only on sv(T) registers, no LDS) — pure wave-local reordering.
__launch_bounds__(256, 2)
__global__ void attn_p12_k(const float* __restrict__ Qg, const short* __restrict__ Kbp,
                           const short* __restrict__ Vtb, const float* __restrict__ Mg,
                           float* __restrict__ Og, const int* __restrict__ flagp)
{
  __shared__ __align__(16) short Kl[2][KVB*HD];   // [64][128] bf16, 16-slot row XOR
  __shared__ __align__(16) short Vl[2][HD*KVB];   // [128][64] bf16 (V^T), 8-slot XOR

  const int tid = threadIdx.x;
  const int w = tid >> 6, lane = tid & 63;
  const int l31 = lane & 31, hi1 = lane >> 5;
  const int swzk = (l31 & 15) << 3;
  const int swzv = (l31 & 7) << 3;

  int bid = blockIdx.x;
  bid = (bid & 7)*64 + (bid >> 3);          // bijective XCD swizzle (512 % 8 == 0)
  const int bh = bid >> 4;
  const int qt = bid & 15;
  const int b = bh >> 4, h = bh & 15;
  const int mflag = *flagp;
  const int qrow_g = qt*QB + w*32 + l31;

  // Q fragments, pre-scaled by SCL2E (folds softmax scale into QK^T)
  bf16x8 qf[8];
  {
    const float* qrow = Qg + ((size_t)(b*SEQ + qrow_g))*HID + h*HD;
    #pragma unroll
    for (int ks = 0; ks < 8; ++ks){
      float4 a = *(const float4*)(qrow + ks*16 + hi1*8);
      float4 c = *(const float4*)(qrow + ks*16 + hi1*8 + 4);
      bf16x8 q;
      q[0]=f2bf(a.x*SCL2E); q[1]=f2bf(a.y*SCL2E); q[2]=f2bf(a.z*SCL2E); q[3]=f2bf(a.w*SCL2E);
      q[4]=f2bf(c.x*SCL2E); q[5]=f2bf(c.y*SCL2E); q[6]=f2bf(c.z*SCL2E); q[7]=f2bf(c.w*SCL2E);
      qf[ks] = q;
    }
  }

  // staging: pre-swizzled per-lane global source, linear LDS dest
  const short* kbase = Kbp + (size_t)bh*SEQ*HD;
  const short* vbase = Vtb + (size_t)bh*HD*SEQ;
  int koff[4], voff[4], cdst[4];
  #pragma unroll
  for (int c = 0; c < 4; ++c){
    int p = (c*4 + w)*1024 + lane*16;       // byte position in 16KB tile
    cdst[c] = (c*4 + w)*1024;
    int r  = p >> 8;                         // K row (256 B rows)
    int cs = (p & 255) >> 1;
    koff[c] = r*HD + (cs ^ ((r & 15) << 3));
    int d   = p >> 7;                        // V^T row (128 B rows)
    int cs2 = (p & 127) >> 1;
    voff[c] = d*SEQ + (cs2 ^ ((d & 7) << 3));
  }
  auto stageK = [&](int kt){
    const short* ks = kbase + kt*(KVB*HD);
    char* kl = (char*)&Kl[kt & 1][0];
    #pragma unroll
    for (int c = 0; c < 4; ++c) gld_lds16(ks + koff[c], kl + cdst[c]);
  };
  auto stageV = [&](int kt){
    const short* vs = vbase + kt*KVB;
    char* vl = (char*)&Vl[kt & 1][0];
    #pragma unroll
    for (int c = 0; c < 4; ++c) gld_lds16(vs + voff[c], vl + cdst[c]);
  };

  f32x16 acc[4];
  #pragma unroll
  for (int cb = 0; cb < 4; ++cb)
    #pragma unroll
    for (int i = 0; i < 16; ++i) acc[cb][i] = 0.f;
  float m_ = -INFINITY, l_ = 0.f;

  auto qkt = [&](int kt, f32x16& s0, f32x16& s1){
    const short* Kc = &Kl[kt & 1][0];
    f32x16 a0, a1;
    #pragma unroll
    for (int i = 0; i < 16; ++i){ a0[i] = 0.f; a1[i] = 0.f; }
    #pragma unroll
    for (int ks = 0; ks < 8; ++ks){
      int o = (ks*16 + hi1*8) ^ swzk;
      bf16x8 kf0 = *(const bf16x8*)(Kc + l31*HD + o);
      bf16x8 kf1 = *(const bf16x8*)(Kc + (32 + l31)*HD + o);
      a0 = __builtin_amdgcn_mfma_f32_32x32x16_bf16(kf0, qf[ks], a0, 0, 0, 0);
      a1 = __builtin_amdgcn_mfma_f32_32x32x16_bf16(kf1, qf[ks], a1, 0, 0, 0);
    }
    s0 = a0; s1 = a1;
  };

  // prologue: K0,V0,K1 in flight; drain K0 only; first QK^T
  stageK(0); stageV(0); stageK(1);
  asm volatile("s_waitcnt vmcnt(8)" ::: "memory");
  block_barrier();
  f32x16 svE0, svE1, svO0, svO1;
  qkt(0, svE0, svE1);

  // Substep T: stage V(T+1),K(T+2); [+mask add]; PRE-barrier row-max+rescale(T);
  // vmcnt(N); barrier; {QK^T(T+1) || exp+sum+pack(T)}; PV(T); barrier.
#define SUBSTEP(T, C0, C1, N0, N1, DOSV, DOSK, VMC, DOQ, DOBAR) do {              \
    if (DOSV) stageV((T)+1);                                                      \
    if (DOSK) stageK((T)+2);                                                      \
    float p[32];                                                                  \
    if (mflag){                                                                   \
      const float* mrow = Mg + (size_t)qrow_g*SEQ + (T)*KVB;                      \
      _Pragma("unroll")                                                           \
      for (int i = 0; i < 16; ++i){                                               \
        int kv0 = (i&3) + 8*(i>>2) + 4*hi1;                                       \
        p[i]    = C0[i] + mrow[kv0]*L2E;                                          \
        p[16+i] = C1[i] + mrow[32+kv0]*L2E;                                       \
      }                                                                           \
    }                                                                             \
    /* ---- pre-barrier: row-max + (rare) rescale — fills the vmcnt stall ---- */ \
    float pm;                                                                     \
    {                                                                             \
      float t16[16];                                                              \
      if (mflag){                                                                 \
        _Pragma("unroll")                                                         \
        for (int i = 0; i < 16; ++i) t16[i] = fmaxf(p[i], p[i+16]);               \
      } else {                                                                    \
        _Pragma("unroll")                                                         \
        for (int i = 0; i < 16; ++i) t16[i] = fmaxf(C0[i], C1[i]);                \
      }                                                                           \
      float t8[8];                                                                \
      _Pragma("unroll")                                                           \
      for (int i = 0; i < 8; ++i) t8[i] = fmaxf(t16[i], t16[i+8]);                \
      float t4[4];                                                                \
      _Pragma("unroll")                                                           \
      for (int i = 0; i < 4; ++i) t4[i] = fmaxf(t8[i], t8[i+4]);                  \
      pm = fmaxf(fmaxf(t4[0], t4[1]), fmaxf(t4[2], t4[3]));                       \
      uint2v rr = __builtin_amdgcn_permlane32_swap(__float_as_uint(pm), __float_as_uint(pm), false, false); \
      pm = fmaxf(__uint_as_float(rr[0]), __uint_as_float(rr[1]));                 \
    }                                                                             \
    {                                                                             \
      float mn = fmaxf(m_, pm);                                                   \
      if (!__all(pm - m_ <= 8.0f)){                                               \
        float fac = exp2f(m_ - mn);                                               \
        m_ = mn; l_ *= fac;                                                       \
        _Pragma("unroll")                                                         \
        for (int cb = 0; cb < 4; ++cb)                                            \
          _Pragma("unroll")                                                       \
          for (int i = 0; i < 16; ++i) acc[cb][i] *= fac;                         \
      }                                                                           \
    }                                                                             \
    asm volatile("s_waitcnt vmcnt(" VMC ")" ::: "memory");                        \
    block_barrier();                                                              \
    if (DOQ) qkt((T)+1, N0, N1);                                                  \
    /* ---- post-barrier: exp + sum + pack — overlaps qkt(T+1) MFMAs ---- */      \
    {                                                                             \
      float s16[16];                                                              \
      _Pragma("unroll")                                                           \
      for (int i = 0; i < 16; ++i){                                               \
        float e0 = exp2f((mflag ? p[i]    : C0[i]) - m_);                         \
        float e1 = exp2f((mflag ? p[16+i] : C1[i]) - m_);                         \
        p[i] = e0; p[16+i] = e1;                                                  \
        s16[i] = e0 + e1;                                                         \
      }                                                                           \
      float s8[8];                                                                \
      _Pragma("unroll")                                                           \
      for (int i = 0; i < 8; ++i) s8[i] = s16[i] + s16[i+8];                      \
      float s4[4];                                                                \
      _Pragma("unroll")                                                           \
      for (int i = 0; i < 4; ++i) s4[i] = s8[i] + s8[i+4];                        \
      float rs = (s4[0] + s4[1]) + (s4[2] + s4[3]);                               \
      uint2v rr = __builtin_amdgcn_permlane32_swap(__float_as_uint(rs), __float_as_uint(rs), false, false); \
      rs = __uint_as_float(rr[0]) + __uint_as_float(rr[1]);                       \
      l_ += rs;                                                                   \
    }                                                                             \
    bf16x8 pa[4];                                                                 \
    _Pragma("unroll")                                                             \
    for (int sl = 0; sl < 4; ++sl){                                               \
      const int ib = 8*(sl & 1) + 16*(sl >> 1);                                   \
      unsigned A0 = cvtpk(p[ib+0], p[ib+1]);                                      \
      unsigned A1 = cvtpk(p[ib+2], p[ib+3]);                                      \
      unsigned B0 = cvtpk(p[ib+4], p[ib+5]);                                      \
      unsigned B1 = cvtpk(p[ib+6], p[ib+7]);                                      \
      uint2v r0 = __builtin_amdgcn_permlane32_swap(A0, B0, false, false);         \
      uint2v r1 = __builtin_amdgcn_permlane32_swap(A1, B1, false, false);         \
      union { unsigned u[4]; bf16x8 v; } tt;                                      \
      tt.u[0] = r0[0]; tt.u[1] = r1[0]; tt.u[2] = r0[1]; tt.u[3] = r1[1];         \
      pa[sl] = tt.v;                                                              \
    }                                                                             \
    {                                                                             \
      const short* Vc = &Vl[(T) & 1][0];                                          \
      _Pragma("unroll")                                                           \
      for (int sl = 0; sl < 4; ++sl){                                             \
        int o = (sl*16 + hi1*8) ^ swzv;                                           \
        _Pragma("unroll")                                                         \
        for (int cb = 0; cb < 4; ++cb){                                           \
          bf16x8 vf = *(const bf16x8*)(Vc + (cb*32 + l31)*KVB + o);               \
          acc[cb] = __builtin_amdgcn_mfma_f32_32x32x16_bf16(vf, pa[sl], acc[cb], 0, 0, 0); \
        }                                                                         \
      }                                                                           \
    }                                                                             \
    if (DOBAR) block_barrier();                                                   \
  } while(0)

  for (int t = 0; t < NKT-2; t += 2){
    SUBSTEP(t,   svE0, svE1, svO0, svO1, 1, 1, "8", 1, 1);
    SUBSTEP(t+1, svO0, svO1, svE0, svE1, 1, 1, "8", 1, 1);
  }
  SUBSTEP(NKT-2, svE0, svE1, svO0, svO1, 1, 0, "4", 1, 1);
  SUBSTEP(NKT-1, svO0, svO1, svE0, svE1, 0, 0, "0", 0, 0);
#undef SUBSTEP

  // ---- epilogue: lane owns q=l31; acc reg = d_local (runs of 4) ----
  float inv = 1.0f / l_;
  float* orow = Og + ((size_t)(b*SEQ + qrow_g))*HID + h*HD;
  #pragma unroll
  for (int cb = 0; cb < 4; ++cb)
    #pragma unroll
    for (int g = 0; g < 4; ++g){
      float4 o;
      o.x = acc[cb][g*4+0]*inv; o.y = acc[cb][g*4+1]*inv;
      o.z = acc[cb][g*4+2]*inv; o.w = acc[cb][g*4+3]*inv;
      *(float4*)(orow + cb*32 + g*8 + 4*hi1) = o;
    }
}

// ---- round-1 fp32-input fallback (used when ws too small) ----
__launch_bounds__(256)
__global__ void attn_f32_k(const float* __restrict__ Qg, const float* __restrict__ Kg,
                           const float* __restrict__ Vg, const float* __restrict__ Mg,
                           float* __restrict__ Og, const int* __restrict__ flagp)
{
  __shared__ __align__(16) short Kl[64*HD];
  __shared__ __align__(16) short Vt[HD*64];
  __shared__ __align__(16) short Pl[4][16*64];

  const int tid  = threadIdx.x;
  const int w    = tid >> 6;
  const int lane = tid & 63;
  const int lo   = lane & 15;
  const int hi   = lane >> 4;

  int bid = blockIdx.x;
  bid = (bid & 7)*128 + (bid >> 3);
  const int bh = bid >> 5;
  const int qt = bid & 31;
  const int b  = bh >> 4;
  const int h  = bh & 15;
  const int mflag = *flagp;

  bf16x8 qf[4];
  {
    const float* qrow = Qg + ((size_t)(b*SEQ + qt*QBLK + w*16 + lo))*HID + h*HD;
    #pragma unroll
    for (int kc = 0; kc < 4; ++kc){
      float4 v0 = *(const float4*)(qrow + kc*32 + hi*8);
      float4 v1 = *(const float4*)(qrow + kc*32 + hi*8 + 4);
      bf16x8 q;
      q[0]=f2bf(v0.x); q[1]=f2bf(v0.y); q[2]=f2bf(v0.z); q[3]=f2bf(v0.w);
      q[4]=f2bf(v1.x); q[5]=f2bf(v1.y); q[6]=f2bf(v1.z); q[7]=f2bf(v1.w);
      qf[kc] = q;
    }
  }

  f32x4 acc[8];
  #pragma unroll
  for (int i = 0; i < 8; ++i){ acc[i][0]=0.f; acc[i][1]=0.f; acc[i][2]=0.f; acc[i][3]=0.f; }
  float mrow[4] = {-INFINITY, -INFINITY, -INFINITY, -INFINITY};
  float lrow[4] = {0.f, 0.f, 0.f, 0.f};

  const float* kb = Kg + ((size_t)b*SEQ)*HID + h*HD;
  const float* vb = Vg + ((size_t)b*SEQ)*HID + h*HD;

  for (int kt = 0; kt < SEQ/64; ++kt){
    __syncthreads();
    {
      const float* kp = kb + (size_t)(kt*64)*HID;
      #pragma unroll
      for (int i = 0; i < 8; ++i){
        int idx = tid + i*256;
        int r  = idx >> 5;
        int c4 = idx & 31;
        float4 v = *(const float4*)(kp + (size_t)r*HID + c4*4);
        int sidx = (r*HD + c4*4) ^ ((r & 7) << 3);
        short* dst = &Kl[sidx];
        dst[0]=f2bf(v.x); dst[1]=f2bf(v.y); dst[2]=f2bf(v.z); dst[3]=f2bf(v.w);
      }
      const float* vp = vb + (size_t)(kt*64)*HID;
      #pragma unroll
      for (int u = 0; u < 4; ++u){
        int unit = tid + u*256;
        int d   = unit & 127;
        int g   = unit >> 7;
        int kv0 = g*8;
        bf16x8 pk;
        #pragma unroll
        for (int j = 0; j < 8; ++j)
          pk[j] = f2bf(vp[(size_t)(kv0 + j)*HID + d]);
        int sidx = (d*64 + kv0) ^ ((d & 7) << 3);
        *(bf16x8*)(&Vt[sidx]) = pk;
      }
    }
    __syncthreads();

    f32x4 sv[4];
    #pragma unroll
    for (int nb = 0; nb < 4; ++nb){ sv[nb][0]=0.f; sv[nb][1]=0.f; sv[nb][2]=0.f; sv[nb][3]=0.f; }
    #pragma unroll
    for (int nb = 0; nb < 4; ++nb){
      int krow = nb*16 + lo;
      #pragma unroll
      for (int kc = 0; kc < 4; ++kc){
        int sidx = (krow*HD + kc*32 + hi*8) ^ ((krow & 7) << 3);
        bf16x8 kf = *(const bf16x8*)(&Kl[sidx]);
        sv[nb] = __builtin_amdgcn_mfma_f32_16x16x32_bf16(qf[kc], kf, sv[nb], 0, 0, 0);
      }
    }

    float p[4][4];
    if (mflag){
      #pragma unroll
      for (int nb = 0; nb < 4; ++nb)
        #pragma unroll
        for (int r = 0; r < 4; ++r){
          float mv = Mg[(size_t)(qt*QBLK + w*16 + hi*4 + r)*SEQ + kt*64 + nb*16 + lo];
          p[nb][r] = sv[nb][r]*SCL2E + mv*L2E;
        }
    } else {
      #pragma unroll
      for (int nb = 0; nb < 4; ++nb)
        #pragma unroll
        for (int r = 0; r < 4; ++r)
          p[nb][r] = sv[nb][r]*SCL2E;
    }

    #pragma unroll
    for (int r = 0; r < 4; ++r){
      float mx = fmaxf(fmaxf(p[0][r], p[1][r]), fmaxf(p[2][r], p[3][r]));
      mx = fmaxf(mx, __shfl_xor(mx, 1, 64));
      mx = fmaxf(mx, __shfl_xor(mx, 2, 64));
      mx = fmaxf(mx, __shfl_xor(mx, 4, 64));
      mx = fmaxf(mx, __shfl_xor(mx, 8, 64));
      float mn  = fmaxf(mrow[r], mx);
      float fac = exp2f(mrow[r] - mn);
      mrow[r] = mn;
      lrow[r] *= fac;
      #pragma unroll
      for (int oc = 0; oc < 8; ++oc) acc[oc][r] *= fac;
      float rsv = 0.f;
      #pragma unroll
      for (int nb = 0; nb < 4; ++nb){
        float e = exp2f(p[nb][r] - mn);
        p[nb][r] = e;
        rsv += e;
      }
      rsv += __shfl_xor(rsv, 1, 64);
      rsv += __shfl_xor(rsv, 2, 64);
      rsv += __shfl_xor(rsv, 4, 64);
      rsv += __shfl_xor(rsv, 8, 64);
      lrow[r] += rsv;
    }

    short* myP = &Pl[w][0];
    #pragma unroll
    for (int nb = 0; nb < 4; ++nb)
      #pragma unroll
      for (int r = 0; r < 4; ++r){
        int row = hi*4 + r;
        int sidx = (row*64 + nb*16 + lo) ^ ((row & 7) << 3);
        myP[sidx] = f2bf(p[nb][r]);
      }

    #pragma unroll
    for (int kc2 = 0; kc2 < 2; ++kc2){
      int sA = (lo*64 + kc2*32 + hi*8) ^ ((lo & 7) << 3);
      bf16x8 pa = *(const bf16x8*)(&myP[sA]);
      #pragma unroll
      for (int oc = 0; oc < 8; ++oc){
        int vrow = oc*16 + lo;
        int sB = (vrow*64 + kc2*32 + hi*8) ^ ((vrow & 7) << 3);
        bf16x8 vf = *(const bf16x8*)(&Vt[sB]);
        acc[oc] = __builtin_amdgcn_mfma_f32_16x16x32_bf16(pa, vf, acc[oc], 0, 0, 0);
      }
    }
  }

  float* orow = Og + ((size_t)(b*SEQ + qt*QBLK + w*16))*HID + h*HD;
  #pragma unroll
  for (int r = 0; r < 4; ++r){
    float inv = 1.0f / lrow[r];
    #pragma unroll
    for (int oc = 0; oc < 8; ++oc)
      orow[(size_t)(hi*4 + r)*HID + oc*16 + lo] = acc[oc][r]*inv;
  }
}

extern "C" void kernel_launch(void* const* d_in, const int* in_sizes, int n_in,
                              void* d_out, int out_size, void* d_ws, size_t ws_size,
                              hipStream_t stream)
{
  const float* Qg = (const float*)d_in[0];
  const float* Kg = (const float*)d_in[1];
  const float* Vg = (const float*)d_in[2];
  const float* Mg = (const float*)d_in[3];
  float* Og = (float*)d_out;
  int* flag = (int*)d_ws;

  const size_t plane = (size_t)2*NH*SEQ*HD;        // elements per bf16 tensor
  const size_t need = 64 + 2*plane*sizeof(short);  // K + V^T, ~33.6 MB

  hipMemsetAsync(d_ws, 0, 4, stream);

  if (ws_size >= need){
    short* Kb = (short*)((char*)d_ws + 64);
    short* Vt = Kb + plane;
    hipLaunchKernelGGL(cvt_kv_k, dim3(3072), dim3(256), 0, stream, Kg, Vg, Mg, Kb, Vt, flag);
    hipLaunchKernelGGL(attn_p12_k, dim3(512), dim3(256), 0, stream, Qg, Kb, Vt, Mg, Og, flag);
  } else {
    hipLaunchKernelGGL(mask_scan_k, dim3(256), dim3(256), 0, stream, Mg, SEQ*SEQ/4, flag);
    hipLaunchKernelGGL(attn_f32_k, dim3(32*32), dim3(256), 0, stream, Qg, Kg, Vg, Mg, Og, flag);
  }
}

// Round 13
// 123.228 us; speedup vs baseline: 2.7970x; 2.7970x over previous
//
#include <hip/hip_runtime.h>
#include <hip/hip_bf16.h>
#include <math.h>

#define SEQ 2048
#define NH 16
#define HD 128
#define HID 2048
#define KVB 64
#define NKT (SEQ/KVB)
#define QB 128              // q rows per block (4 waves x 32)
#define QBLK 64             // f32 fallback kernel

typedef __attribute__((ext_vector_type(8))) short bf16x8;
typedef __attribute__((ext_vector_type(4))) short bf16x4;
typedef __attribute__((ext_vector_type(4))) float f32x4;
typedef __attribute__((ext_vector_type(16))) float f32x16;
typedef __attribute__((ext_vector_type(2))) unsigned uint2v;

#define SCL2E 0.1275310261f            // (1/sqrt(128)) * log2(e)
#define L2E   1.4426950408889634f

__device__ __forceinline__ short f2bf(float x){
  __hip_bfloat16 h = __float2bfloat16(x);
  return *reinterpret_cast<short*>(&h);
}
__device__ __forceinline__ unsigned cvtpk(float lo, float hi){
  unsigned r;
  asm("v_cvt_pk_bf16_f32 %0, %1, %2" : "=v"(r) : "v"(lo), "v"(hi));
  return r;
}
__device__ __forceinline__ void gld_lds16(const void* g, void* l){
  __builtin_amdgcn_global_load_lds((const __attribute__((address_space(1))) void*)g,
                                   (__attribute__((address_space(3))) void*)l, 16, 0, 0);
}
// s_barrier is NOT a compiler memory fence (round-8 lesson): pin both sides.
__device__ __forceinline__ void block_barrier(){
  asm volatile("" ::: "memory");
  __builtin_amdgcn_sched_barrier(0);
  __builtin_amdgcn_s_barrier();
  __builtin_amdgcn_sched_barrier(0);
  asm volatile("" ::: "memory");
}

// ---- fused pre-pass + mask scan ----
// all blocks: grid-stride scan of mask (flag |= any nonzero)
// blocks [0,2048):   K  fp32 [b][s][h*d] -> bf16 [b][h][s][d]
// blocks [2048,3072): V  fp32 [b][s][h*d] -> bf16 V^T [b][h][d][s]
__global__ void cvt_kv_k(const float* __restrict__ Kg, const float* __restrict__ Vg,
                         const float* __restrict__ Mg,
                         short* __restrict__ Kb, short* __restrict__ Vt,
                         int* __restrict__ flag){
  __shared__ short T[64*HD];
  const int tid = threadIdx.x;
  {
    // mask scan slice (16 MB over 3072 blocks)
    const int n4m = SEQ*SEQ/4;
    int any = 0;
    const float4* m4 = (const float4*)Mg;
    for (int i = blockIdx.x*256 + tid; i < n4m; i += 3072*256){
      float4 v = m4[i];
      any |= (v.x != 0.f) | (v.y != 0.f) | (v.z != 0.f) | (v.w != 0.f);
    }
    if (__ballot(any) != 0ull && (tid & 63) == 0) atomicOr(flag, 1);
  }
  if (blockIdx.x < 2048){
    const int n4 = (2*SEQ*HID)/4;
    for (int i = blockIdx.x*256 + tid; i < n4; i += 2048*256){
      int i4 = i*4;
      int b   = i4 >> 22;
      int rem = i4 & ((1<<22)-1);
      int s   = rem >> 11;
      int hd  = rem & 2047;
      int h = hd >> 7, d = hd & 127;
      float4 v = *(const float4*)(Kg + i4);
      bf16x4 o; o[0]=f2bf(v.x); o[1]=f2bf(v.y); o[2]=f2bf(v.z); o[3]=f2bf(v.w);
      *(bf16x4*)(Kb + ((size_t)((b*NH + h)*SEQ + s))*HD + d) = o;
    }
  } else {
    const int bid = blockIdx.x - 2048;
    const int bh = bid >> 5, st = bid & 31;
    const int b = bh >> 4, h = bh & 15;
    const int s0 = st*64;
    const float* vp = Vg + ((size_t)(b*SEQ + s0))*HID + h*HD;
    #pragma unroll
    for (int i = 0; i < 8; ++i){
      int idx = tid + i*256;
      int r = idx >> 5, c4 = idx & 31;
      float4 v = *(const float4*)(vp + (size_t)r*HID + c4*4);
      int X = ((r & 7) ^ ((r >> 3) & 7)) << 3;
      bf16x4 o; o[0]=f2bf(v.x); o[1]=f2bf(v.y); o[2]=f2bf(v.z); o[3]=f2bf(v.w);
      *(bf16x4*)(&T[r*HD + ((c4*4) ^ X)]) = o;
    }
    __syncthreads();
    short* op = Vt + ((size_t)bh*HD)*SEQ + s0;
    #pragma unroll
    for (int u = 0; u < 4; ++u){
      int unit = tid + u*256;
      int sb = unit & 7, d = unit >> 3;
      bf16x8 pk;
      #pragma unroll
      for (int j = 0; j < 8; ++j)
        pk[j] = T[(sb*8 + j)*HD + (d ^ (((j ^ sb) & 7) << 3))];
      *(bf16x8*)(op + (size_t)d*SEQ + sb*8) = pk;
    }
  }
}

// standalone mask scan (fallback path only)
__global__ void mask_scan_k(const float* __restrict__ m, int n4, int* __restrict__ flag){
  int any = 0;
  const float4* m4 = (const float4*)m;
  for (int i = blockIdx.x*blockDim.x + threadIdx.x; i < n4; i += gridDim.x*blockDim.x){
    float4 v = m4[i];
    any |= (v.x != 0.f) | (v.y != 0.f) | (v.z != 0.f) | (v.w != 0.f);
  }
  if (__ballot(any) != 0ull && (threadIdx.x & 63) == 0) atomicOr(flag, 1);
}

// ---- main: 512 blocks, 4 waves x 32 q-rows, counted-vmcnt software pipeline ----
__launch_bounds__(256, 2)
__global__ void attn_p10_k(const float* __restrict__ Qg, const short* __restrict__ Kbp,
                           const short* __restrict__ Vtb, const float* __restrict__ Mg,
                           float* __restrict__ Og, const int* __restrict__ flagp)
{
  __shared__ __align__(16) short Kl[2][KVB*HD];   // [64][128] bf16, 16-slot row XOR
  __shared__ __align__(16) short Vl[2][HD*KVB];   // [128][64] bf16 (V^T), 8-slot XOR

  const int tid = threadIdx.x;
  const int w = tid >> 6, lane = tid & 63;
  const int l31 = lane & 31, hi1 = lane >> 5;
  const int swzk = (l31 & 15) << 3;
  const int swzv = (l31 & 7) << 3;

  int bid = blockIdx.x;
  bid = (bid & 7)*64 + (bid >> 3);          // bijective XCD swizzle (512 % 8 == 0)
  const int bh = bid >> 4;
  const int qt = bid & 15;
  const int b = bh >> 4, h = bh & 15;
  const int mflag = *flagp;
  const int qrow_g = qt*QB + w*32 + l31;

  // Q fragments, pre-scaled by SCL2E (folds softmax scale into QK^T)
  bf16x8 qf[8];
  {
    const float* qrow = Qg + ((size_t)(b*SEQ + qrow_g))*HID + h*HD;
    #pragma unroll
    for (int ks = 0; ks < 8; ++ks){
      float4 a = *(const float4*)(qrow + ks*16 + hi1*8);
      float4 c = *(const float4*)(qrow + ks*16 + hi1*8 + 4);
      bf16x8 q;
      q[0]=f2bf(a.x*SCL2E); q[1]=f2bf(a.y*SCL2E); q[2]=f2bf(a.z*SCL2E); q[3]=f2bf(a.w*SCL2E);
      q[4]=f2bf(c.x*SCL2E); q[5]=f2bf(c.y*SCL2E); q[6]=f2bf(c.z*SCL2E); q[7]=f2bf(c.w*SCL2E);
      qf[ks] = q;
    }
  }

  // staging: pre-swizzled per-lane global source, linear LDS dest
  const short* kbase = Kbp + (size_t)bh*SEQ*HD;
  const short* vbase = Vtb + (size_t)bh*HD*SEQ;
  int koff[4], voff[4], cdst[4];
  #pragma unroll
  for (int c = 0; c < 4; ++c){
    int p = (c*4 + w)*1024 + lane*16;       // byte position in 16KB tile
    cdst[c] = (c*4 + w)*1024;
    int r  = p >> 8;                         // K row (256 B rows)
    int cs = (p & 255) >> 1;
    koff[c] = r*HD + (cs ^ ((r & 15) << 3));
    int d   = p >> 7;                        // V^T row (128 B rows)
    int cs2 = (p & 127) >> 1;
    voff[c] = d*SEQ + (cs2 ^ ((d & 7) << 3));
  }
  auto stageK = [&](int kt){
    const short* ks = kbase + kt*(KVB*HD);
    char* kl = (char*)&Kl[kt & 1][0];
    #pragma unroll
    for (int c = 0; c < 4; ++c) gld_lds16(ks + koff[c], kl + cdst[c]);
  };
  auto stageV = [&](int kt){
    const short* vs = vbase + kt*KVB;
    char* vl = (char*)&Vl[kt & 1][0];
    #pragma unroll
    for (int c = 0; c < 4; ++c) gld_lds16(vs + voff[c], vl + cdst[c]);
  };

  f32x16 acc[4];
  #pragma unroll
  for (int cb = 0; cb < 4; ++cb)
    #pragma unroll
    for (int i = 0; i < 16; ++i) acc[cb][i] = 0.f;
  float m_ = -INFINITY, l_ = 0.f;

  auto qkt = [&](int kt, f32x16& s0, f32x16& s1){
    const short* Kc = &Kl[kt & 1][0];
    f32x16 a0, a1;
    #pragma unroll
    for (int i = 0; i < 16; ++i){ a0[i] = 0.f; a1[i] = 0.f; }
    #pragma unroll
    for (int ks = 0; ks < 8; ++ks){
      int o = (ks*16 + hi1*8) ^ swzk;
      bf16x8 kf0 = *(const bf16x8*)(Kc + l31*HD + o);
      bf16x8 kf1 = *(const bf16x8*)(Kc + (32 + l31)*HD + o);
      a0 = __builtin_amdgcn_mfma_f32_32x32x16_bf16(kf0, qf[ks], a0, 0, 0, 0);
      a1 = __builtin_amdgcn_mfma_f32_32x32x16_bf16(kf1, qf[ks], a1, 0, 0, 0);
    }
    s0 = a0; s1 = a1;
  };

  // prologue: K0,V0,K1 in flight; drain K0 only; first QK^T
  stageK(0); stageV(0); stageK(1);
  asm volatile("s_waitcnt vmcnt(8)" ::: "memory");
  block_barrier();
  f32x16 svE0, svE1, svO0, svO1;
  qkt(0, svE0, svE1);

  // Substep T: stages V(T+1),K(T+2); drains V(T),K(T+1) BEFORE barrier (cross-wave
  // safe); then {QK^T(T+1) || softmax(T)} in one region; pack; PV(T); barrier.
#define SUBSTEP(T, C0, C1, N0, N1, DOSV, DOSK, VMC, DOQ, DOBAR) do {              \
    if (DOSV) stageV((T)+1);                                                      \
    if (DOSK) stageK((T)+2);                                                      \
    float p[32];                                                                  \
    if (mflag){                                                                   \
      const float* mrow = Mg + (size_t)qrow_g*SEQ + (T)*KVB;                      \
      _Pragma("unroll")                                                           \
      for (int i = 0; i < 16; ++i){                                               \
        int kv0 = (i&3) + 8*(i>>2) + 4*hi1;                                       \
        p[i]    = C0[i] + mrow[kv0]*L2E;                                          \
        p[16+i] = C1[i] + mrow[32+kv0]*L2E;                                       \
      }                                                                           \
    } else {                                                                      \
      _Pragma("unroll")                                                           \
      for (int i = 0; i < 16; ++i){ p[i] = C0[i]; p[16+i] = C1[i]; }              \
    }                                                                             \
    asm volatile("s_waitcnt vmcnt(" VMC ")" ::: "memory");                        \
    block_barrier();                                                              \
    if (DOQ) qkt((T)+1, N0, N1);                                                  \
    float pm;                                                                     \
    {                                                                             \
      float t16[16];                                                              \
      _Pragma("unroll")                                                           \
      for (int i = 0; i < 16; ++i) t16[i] = fmaxf(p[i], p[i+16]);                 \
      float t8[8];                                                                \
      _Pragma("unroll")                                                           \
      for (int i = 0; i < 8; ++i) t8[i] = fmaxf(t16[i], t16[i+8]);                \
      float t4[4];                                                                \
      _Pragma("unroll")                                                           \
      for (int i = 0; i < 4; ++i) t4[i] = fmaxf(t8[i], t8[i+4]);                  \
      pm = fmaxf(fmaxf(t4[0], t4[1]), fmaxf(t4[2], t4[3]));                       \
      uint2v rr = __builtin_amdgcn_permlane32_swap(__float_as_uint(pm), __float_as_uint(pm), false, false); \
      pm = fmaxf(__uint_as_float(rr[0]), __uint_as_float(rr[1]));                 \
    }                                                                             \
    float mn = fmaxf(m_, pm);                                                     \
    if (!__all(pm - m_ <= 8.0f)){                                                 \
      float fac = exp2f(m_ - mn);                                                 \
      m_ = mn; l_ *= fac;                                                         \
      _Pragma("unroll")                                                           \
      for (int cb = 0; cb < 4; ++cb)                                              \
        _Pragma("unroll")                                                         \
        for (int i = 0; i < 16; ++i) acc[cb][i] *= fac;                           \
    }                                                                             \
    {                                                                             \
      float s16[16];                                                              \
      _Pragma("unroll")                                                           \
      for (int i = 0; i < 16; ++i){                                               \
        float e0 = exp2f(p[i] - m_);                                              \
        float e1 = exp2f(p[i+16] - m_);                                           \
        p[i] = e0; p[16+i] = e1;                                                  \
        s16[i] = e0 + e1;                                                         \
      }                                                                           \
      float s8[8];                                                                \
      _Pragma("unroll")                                                           \
      for (int i = 0; i < 8; ++i) s8[i] = s16[i] + s16[i+8];                      \
      float s4[4];                                                                \
      _Pragma("unroll")                                                           \
      for (int i = 0; i < 4; ++i) s4[i] = s8[i] + s8[i+4];                        \
      float rs = (s4[0] + s4[1]) + (s4[2] + s4[3]);                               \
      uint2v rr = __builtin_amdgcn_permlane32_swap(__float_as_uint(rs), __float_as_uint(rs), false, false); \
      rs = __uint_as_float(rr[0]) + __uint_as_float(rr[1]);                       \
      l_ += rs;                                                                   \
    }                                                                             \
    bf16x8 pa[4];                                                                 \
    _Pragma("unroll")                                                             \
    for (int sl = 0; sl < 4; ++sl){                                               \
      const int ib = 8*(sl & 1) + 16*(sl >> 1);                                   \
      unsigned A0 = cvtpk(p[ib+0], p[ib+1]);                                      \
      unsigned A1 = cvtpk(p[ib+2], p[ib+3]);                                      \
      unsigned B0 = cvtpk(p[ib+4], p[ib+5]);                                      \
      unsigned B1 = cvtpk(p[ib+6], p[ib+7]);                                      \
      uint2v r0 = __builtin_amdgcn_permlane32_swap(A0, B0, false, false);         \
      uint2v r1 = __builtin_amdgcn_permlane32_swap(A1, B1, false, false);         \
      union { unsigned u[4]; bf16x8 v; } tt;                                      \
      tt.u[0] = r0[0]; tt.u[1] = r1[0]; tt.u[2] = r0[1]; tt.u[3] = r1[1];         \
      pa[sl] = tt.v;                                                              \
    }                                                                             \
    {                                                                             \
      const short* Vc = &Vl[(T) & 1][0];                                          \
      _Pragma("unroll")                                                           \
      for (int sl = 0; sl < 4; ++sl){                                             \
        int o = (sl*16 + hi1*8) ^ swzv;                                           \
        _Pragma("unroll")                                                         \
        for (int cb = 0; cb < 4; ++cb){                                           \
          bf16x8 vf = *(const bf16x8*)(Vc + (cb*32 + l31)*KVB + o);               \
          acc[cb] = __builtin_amdgcn_mfma_f32_32x32x16_bf16(vf, pa[sl], acc[cb], 0, 0, 0); \
        }                                                                         \
      }                                                                           \
    }                                                                             \
    if (DOBAR) block_barrier();                                                   \
  } while(0)

  for (int t = 0; t < NKT-2; t += 2){
    SUBSTEP(t,   svE0, svE1, svO0, svO1, 1, 1, "8", 1, 1);
    SUBSTEP(t+1, svO0, svO1, svE0, svE1, 1, 1, "8", 1, 1);
  }
  SUBSTEP(NKT-2, svE0, svE1, svO0, svO1, 1, 0, "4", 1, 1);
  SUBSTEP(NKT-1, svO0, svO1, svE0, svE1, 0, 0, "0", 0, 0);
#undef SUBSTEP

  // ---- epilogue: lane owns q=l31; acc reg = d_local (runs of 4) ----
  float inv = 1.0f / l_;
  float* orow = Og + ((size_t)(b*SEQ + qrow_g))*HID + h*HD;
  #pragma unroll
  for (int cb = 0; cb < 4; ++cb)
    #pragma unroll
    for (int g = 0; g < 4; ++g){
      float4 o;
      o.x = acc[cb][g*4+0]*inv; o.y = acc[cb][g*4+1]*inv;
      o.z = acc[cb][g*4+2]*inv; o.w = acc[cb][g*4+3]*inv;
      *(float4*)(orow + cb*32 + g*8 + 4*hi1) = o;
    }
}

// ---- round-1 fp32-input fallback (used when ws too small) ----
__launch_bounds__(256)
__global__ void attn_f32_k(const float* __restrict__ Qg, const float* __restrict__ Kg,
                           const float* __restrict__ Vg, const float* __restrict__ Mg,
                           float* __restrict__ Og, const int* __restrict__ flagp)
{
  __shared__ __align__(16) short Kl[64*HD];
  __shared__ __align__(16) short Vt[HD*64];
  __shared__ __align__(16) short Pl[4][16*64];

  const int tid  = threadIdx.x;
  const int w    = tid >> 6;
  const int lane = tid & 63;
  const int lo   = lane & 15;
  const int hi   = lane >> 4;

  int bid = blockIdx.x;
  bid = (bid & 7)*128 + (bid >> 3);
  const int bh = bid >> 5;
  const int qt = bid & 31;
  const int b  = bh >> 4;
  const int h  = bh & 15;
  const int mflag = *flagp;

  bf16x8 qf[4];
  {
    const float* qrow = Qg + ((size_t)(b*SEQ + qt*QBLK + w*16 + lo))*HID + h*HD;
    #pragma unroll
    for (int kc = 0; kc < 4; ++kc){
      float4 v0 = *(const float4*)(qrow + kc*32 + hi*8);
      float4 v1 = *(const float4*)(qrow + kc*32 + hi*8 + 4);
      bf16x8 q;
      q[0]=f2bf(v0.x); q[1]=f2bf(v0.y); q[2]=f2bf(v0.z); q[3]=f2bf(v0.w);
      q[4]=f2bf(v1.x); q[5]=f2bf(v1.y); q[6]=f2bf(v1.z); q[7]=f2bf(v1.w);
      qf[kc] = q;
    }
  }

  f32x4 acc[8];
  #pragma unroll
  for (int i = 0; i < 8; ++i){ acc[i][0]=0.f; acc[i][1]=0.f; acc[i][2]=0.f; acc[i][3]=0.f; }
  float mrow[4] = {-INFINITY, -INFINITY, -INFINITY, -INFINITY};
  float lrow[4] = {0.f, 0.f, 0.f, 0.f};

  const float* kb = Kg + ((size_t)b*SEQ)*HID + h*HD;
  const float* vb = Vg + ((size_t)b*SEQ)*HID + h*HD;

  for (int kt = 0; kt < SEQ/64; ++kt){
    __syncthreads();
    {
      const float* kp = kb + (size_t)(kt*64)*HID;
      #pragma unroll
      for (int i = 0; i < 8; ++i){
        int idx = tid + i*256;
        int r  = idx >> 5;
        int c4 = idx & 31;
        float4 v = *(const float4*)(kp + (size_t)r*HID + c4*4);
        int sidx = (r*HD + c4*4) ^ ((r & 7) << 3);
        short* dst = &Kl[sidx];
        dst[0]=f2bf(v.x); dst[1]=f2bf(v.y); dst[2]=f2bf(v.z); dst[3]=f2bf(v.w);
      }
      const float* vp = vb + (size_t)(kt*64)*HID;
      #pragma unroll
      for (int u = 0; u < 4; ++u){
        int unit = tid + u*256;
        int d   = unit & 127;
        int g   = unit >> 7;
        int kv0 = g*8;
        bf16x8 pk;
        #pragma unroll
        for (int j = 0; j < 8; ++j)
          pk[j] = f2bf(vp[(size_t)(kv0 + j)*HID + d]);
        int sidx = (d*64 + kv0) ^ ((d & 7) << 3);
        *(bf16x8*)(&Vt[sidx]) = pk;
      }
    }
    __syncthreads();

    f32x4 sv[4];
    #pragma unroll
    for (int nb = 0; nb < 4; ++nb){ sv[nb][0]=0.f; sv[nb][1]=0.f; sv[nb][2]=0.f; sv[nb][3]=0.f; }
    #pragma unroll
    for (int nb = 0; nb < 4; ++nb){
      int krow = nb*16 + lo;
      #pragma unroll
      for (int kc = 0; kc < 4; ++kc){
        int sidx = (krow*HD + kc*32 + hi*8) ^ ((krow & 7) << 3);
        bf16x8 kf = *(const bf16x8*)(&Kl[sidx]);
        sv[nb] = __builtin_amdgcn_mfma_f32_16x16x32_bf16(qf[kc], kf, sv[nb], 0, 0, 0);
      }
    }

    float p[4][4];
    if (mflag){
      #pragma unroll
      for (int nb = 0; nb < 4; ++nb)
        #pragma unroll
        for (int r = 0; r < 4; ++r){
          float mv = Mg[(size_t)(qt*QBLK + w*16 + hi*4 + r)*SEQ + kt*64 + nb*16 + lo];
          p[nb][r] = sv[nb][r]*SCL2E + mv*L2E;
        }
    } else {
      #pragma unroll
      for (int nb = 0; nb < 4; ++nb)
        #pragma unroll
        for (int r = 0; r < 4; ++r)
          p[nb][r] = sv[nb][r]*SCL2E;
    }

    #pragma unroll
    for (int r = 0; r < 4; ++r){
      float mx = fmaxf(fmaxf(p[0][r], p[1][r]), fmaxf(p[2][r], p[3][r]));
      mx = fmaxf(mx, __shfl_xor(mx, 1, 64));
      mx = fmaxf(mx, __shfl_xor(mx, 2, 64));
      mx = fmaxf(mx, __shfl_xor(mx, 4, 64));
      mx = fmaxf(mx, __shfl_xor(mx, 8, 64));
      float mn  = fmaxf(mrow[r], mx);
      float fac = exp2f(mrow[r] - mn);
      mrow[r] = mn;
      lrow[r] *= fac;
      #pragma unroll
      for (int oc = 0; oc < 8; ++oc) acc[oc][r] *= fac;
      float rsv = 0.f;
      #pragma unroll
      for (int nb = 0; nb < 4; ++nb){
        float e = exp2f(p[nb][r] - mn);
        p[nb][r] = e;
        rsv += e;
      }
      rsv += __shfl_xor(rsv, 1, 64);
      rsv += __shfl_xor(rsv, 2, 64);
      rsv += __shfl_xor(rsv, 4, 64);
      rsv += __shfl_xor(rsv, 8, 64);
      lrow[r] += rsv;
    }

    short* myP = &Pl[w][0];
    #pragma unroll
    for (int nb = 0; nb < 4; ++nb)
      #pragma unroll
      for (int r = 0; r < 4; ++r){
        int row = hi*4 + r;
        int sidx = (row*64 + nb*16 + lo) ^ ((row & 7) << 3);
        myP[sidx] = f2bf(p[nb][r]);
      }

    #pragma unroll
    for (int kc2 = 0; kc2 < 2; ++kc2){
      int sA = (lo*64 + kc2*32 + hi*8) ^ ((lo & 7) << 3);
      bf16x8 pa = *(const bf16x8*)(&myP[sA]);
      #pragma unroll
      for (int oc = 0; oc < 8; ++oc){
        int vrow = oc*16 + lo;
        int sB = (vrow*64 + kc2*32 + hi*8) ^ ((vrow & 7) << 3);
        bf16x8 vf = *(const bf16x8*)(&Vt[sB]);
        acc[oc] = __builtin_amdgcn_mfma_f32_16x16x32_bf16(pa, vf, acc[oc], 0, 0, 0);
      }
    }
  }

  float* orow = Og + ((size_t)(b*SEQ + qt*QBLK + w*16))*HID + h*HD;
  #pragma unroll
  for (int r = 0; r < 4; ++r){
    float inv = 1.0f / lrow[r];
    #pragma unroll
    for (int oc = 0; oc < 8; ++oc)
      orow[(size_t)(hi*4 + r)*HID + oc*16 + lo] = acc[oc][r]*inv;
  }
}

extern "C" void kernel_launch(void* const* d_in, const int* in_sizes, int n_in,
                              void* d_out, int out_size, void* d_ws, size_t ws_size,
                              hipStream_t stream)
{
  const float* Qg = (const float*)d_in[0];
  const float* Kg = (const float*)d_in[1];
  const float* Vg = (const float*)d_in[2];
  const float* Mg = (const float*)d_in[3];
  float* Og = (float*)d_out;
  int* flag = (int*)d_ws;

  const size_t plane = (size_t)2*NH*SEQ*HD;        // elements per bf16 tensor
  const size_t need = 64 + 2*plane*sizeof(short);  // K + V^T, ~33.6 MB

  hipMemsetAsync(d_ws, 0, 4, stream);

  if (ws_size >= need){
    short* Kb = (short*)((char*)d_ws + 64);
    short* Vt = Kb + plane;
    hipLaunchKernelGGL(cvt_kv_k, dim3(3072), dim3(256), 0, stream, Kg, Vg, Mg, Kb, Vt, flag);
    hipLaunchKernelGGL(attn_p10_k, dim3(512), dim3(256), 0, stream, Qg, Kb, Vt, Mg, Og, flag);
  } else {
    hipLaunchKernelGGL(mask_scan_k, dim3(256), dim3(256), 0, stream, Mg, SEQ*SEQ/4, flag);
    hipLaunchKernelGGL(attn_f32_k, dim3(32*32), dim3(256), 0, stream, Qg, Kg, Vg, Mg, Og, flag);
  }
}